// Round 1
// baseline (160.536 us; speedup 1.0000x reference)
//
#include <hip/hip_runtime.h>
#include <math.h>

// Problem constants (fixed by the reference).
#define TOK   16
#define TOPA  2
#define NPAIR (TOK * TOPA)   // 32
#define DIM   1024
#define INTER 2816
#define NEXP  8

#define K1_RPB 16   // rows of INTER per block (4 waves * 4 iters)
#define K2_RPB 16   // rows of DIM per block
#define K2_CHUNK 8  // pairs staged in LDS at once (8*2816*4 = 90112 B)

// ---------------------------------------------------------------------------
// Kernel 1: for each pair p=(t,a) routed to expert e, compute
//   h[p][o] = silu(x[t] . w1[e][o]) * (x[t] . w3[e][o])
// grid: (INTER/K1_RPB, NEXP), block: 256 (4 waves).
// Dynamic LDS: x staged [TOK][DIM] f32 = 64 KiB.
// ---------------------------------------------------------------------------
__global__ __launch_bounds__(256) void moe_gate_up(
    const float* __restrict__ x,     // [TOK][DIM]
    const int*   __restrict__ eidx,  // [TOK][TOPA]
    const float* __restrict__ w1,    // [NEXP][INTER][DIM]
    const float* __restrict__ w3,    // [NEXP][INTER][DIM]
    float*       __restrict__ h)     // [NPAIR][INTER]
{
    extern __shared__ float xs[];    // TOK*DIM floats
    __shared__ int praw[NPAIR];
    __shared__ int plist[NPAIR];
    __shared__ int pcount;

    const int e    = blockIdx.y;
    const int tid  = threadIdx.x;
    const int lane = tid & 63;
    const int wave = tid >> 6;

    if (tid < NPAIR) praw[tid] = eidx[tid];
    __syncthreads();
    if (tid == 0) {
        int c = 0;
        for (int p = 0; p < NPAIR; ++p)
            if (praw[p] == e) plist[c++] = p;
        pcount = c;
    }
    __syncthreads();
    const int np = pcount;
    if (np == 0) return;   // skip this expert's weights entirely

    // Stage all of x into LDS (coalesced float4).
    for (int k = tid; k < TOK * DIM / 4; k += 256) {
        ((float4*)xs)[k] = ((const float4*)x)[k];
    }
    __syncthreads();

    const int row_base = blockIdx.x * K1_RPB;

    #pragma unroll
    for (int it = 0; it < K1_RPB / 4; ++it) {
        const int o = row_base + it * 4 + wave;
        const float* w1r = w1 + ((size_t)e * INTER + o) * DIM;
        const float* w3r = w3 + ((size_t)e * INTER + o) * DIM;

        // Stream one w1 row + one w3 row per wave: 8 coalesced float4 loads.
        float4 wa[4], wb[4];
        #pragma unroll
        for (int k = 0; k < 4; ++k) {
            wa[k] = ((const float4*)w1r)[k * 64 + lane];
            wb[k] = ((const float4*)w3r)[k * 64 + lane];
        }

        for (int pi = 0; pi < np; ++pi) {
            const int p = plist[pi];
            const int t = p >> 1;           // p = t*TOPA + a, TOPA = 2
            const float* xr = xs + (size_t)t * DIM;
            float s1 = 0.f, s3 = 0.f;
            #pragma unroll
            for (int k = 0; k < 4; ++k) {
                const float4 xv = *(const float4*)&xr[k * 256 + lane * 4];
                s1 += wa[k].x * xv.x + wa[k].y * xv.y + wa[k].z * xv.z + wa[k].w * xv.w;
                s3 += wb[k].x * xv.x + wb[k].y * xv.y + wb[k].z * xv.z + wb[k].w * xv.w;
            }
            // 64-lane reduce
            #pragma unroll
            for (int off = 32; off > 0; off >>= 1) {
                s1 += __shfl_xor(s1, off);
                s3 += __shfl_xor(s3, off);
            }
            if (lane == 0) {
                const float g = s1 / (1.f + __expf(-s1));   // silu
                h[(size_t)p * INTER + o] = g * s3;
            }
        }
    }
}

// ---------------------------------------------------------------------------
// Kernel 2: out[p][d] = sum_o h[p][o] * w2[e][d][o]
// grid: (DIM/K2_RPB, NEXP), block: 256 (4 waves).
// Dynamic LDS: h chunk [K2_CHUNK][INTER] f32 = 90112 B.
// ---------------------------------------------------------------------------
__global__ __launch_bounds__(256) void moe_down(
    const float* __restrict__ h,     // [NPAIR][INTER]
    const int*   __restrict__ eidx,  // [TOK][TOPA]
    const float* __restrict__ w2,    // [NEXP][DIM][INTER]
    float*       __restrict__ out)   // [NPAIR][DIM]
{
    extern __shared__ float hs[];    // K2_CHUNK * INTER floats
    __shared__ int praw[NPAIR];
    __shared__ int plist[NPAIR];
    __shared__ int pcount;

    const int e    = blockIdx.y;
    const int tid  = threadIdx.x;
    const int lane = tid & 63;
    const int wave = tid >> 6;

    if (tid < NPAIR) praw[tid] = eidx[tid];
    __syncthreads();
    if (tid == 0) {
        int c = 0;
        for (int p = 0; p < NPAIR; ++p)
            if (praw[p] == e) plist[c++] = p;
        pcount = c;
    }
    __syncthreads();
    const int np = pcount;
    if (np == 0) return;

    const int row_base = blockIdx.x * K2_RPB;

    for (int cs = 0; cs < np; cs += K2_CHUNK) {
        const int cn = min(K2_CHUNK, np - cs);

        __syncthreads();  // make sure previous chunk's readers are done
        // Stage cn pairs' h rows into LDS (coalesced float4).
        for (int k = tid; k < cn * (INTER / 4); k += 256) {
            const int pi   = k / (INTER / 4);
            const int col4 = k % (INTER / 4);
            const int p    = plist[cs + pi];
            ((float4*)(hs + (size_t)pi * INTER))[col4] =
                ((const float4*)(h + (size_t)p * INTER))[col4];
        }
        __syncthreads();

        #pragma unroll
        for (int it = 0; it < K2_RPB / 4; ++it) {
            const int d = row_base + it * 4 + wave;
            const float* w2r = w2 + ((size_t)e * DIM + d) * INTER;

            // Stream one w2 row per wave: 11 coalesced float4 loads (2816 = 11*256).
            float4 wv[11];
            #pragma unroll
            for (int k = 0; k < 11; ++k)
                wv[k] = ((const float4*)w2r)[k * 64 + lane];

            for (int pi = 0; pi < cn; ++pi) {
                const float* hr = hs + (size_t)pi * INTER;
                float s = 0.f;
                #pragma unroll
                for (int k = 0; k < 11; ++k) {
                    const float4 hv = *(const float4*)&hr[k * 256 + lane * 4];
                    s += wv[k].x * hv.x + wv[k].y * hv.y + wv[k].z * hv.z + wv[k].w * hv.w;
                }
                #pragma unroll
                for (int off = 32; off > 0; off >>= 1)
                    s += __shfl_xor(s, off);
                if (lane == 0) {
                    const int p = plist[cs + pi];
                    out[(size_t)p * DIM + d] = s;
                }
            }
        }
    }
}

// ---------------------------------------------------------------------------
extern "C" void kernel_launch(void* const* d_in, const int* in_sizes, int n_in,
                              void* d_out, int out_size, void* d_ws, size_t ws_size,
                              hipStream_t stream) {
    const float* x    = (const float*)d_in[0];
    const int*   eidx = (const int*)  d_in[1];
    const float* w1   = (const float*)d_in[2];
    const float* w2   = (const float*)d_in[3];
    const float* w3   = (const float*)d_in[4];
    float* out = (float*)d_out;
    float* h   = (float*)d_ws;   // [NPAIR][INTER] f32 = 360448 B

    dim3 g1(INTER / K1_RPB, NEXP);
    moe_gate_up<<<g1, 256, TOK * DIM * sizeof(float), stream>>>(x, eidx, w1, w3, h);

    dim3 g2(DIM / K2_RPB, NEXP);
    moe_down<<<g2, 256, K2_CHUNK * INTER * sizeof(float), stream>>>(h, eidx, w2, out);
}

// Round 2
// 59.535 us; speedup vs baseline: 2.6965x; 2.6965x over previous
//
#include <hip/hip_runtime.h>
#include <math.h>

// Problem constants (fixed by the reference).
#define TOK   16
#define TOPA  2
#define NPAIR (TOK * TOPA)   // 32
#define DIM   1024
#define INTER 2816
#define NEXP  8

#define R1 2   // rows of INTER per wave (kernel 1)
#define R2 2   // rows of DIM per wave (kernel 2)

// Build a uniform 32-bit mask of pairs routed to expert e.
__device__ inline unsigned pair_mask(const int* __restrict__ eidx, int e) {
    unsigned mask = 0;
    #pragma unroll
    for (int k = 0; k < NPAIR / 4; ++k) {
        const int4 v = ((const int4*)eidx)[k];
        mask |= (unsigned)(v.x == e) << (4 * k + 0);
        mask |= (unsigned)(v.y == e) << (4 * k + 1);
        mask |= (unsigned)(v.z == e) << (4 * k + 2);
        mask |= (unsigned)(v.w == e) << (4 * k + 3);
    }
    return mask;
}

// ---------------------------------------------------------------------------
// Kernel 1: for each pair p=(t,a) routed to expert e:
//   h[p][o] = silu(x[t] . w1[e][o]) * (x[t] . w3[e][o])
// grid: (INTER/(4*R1), NEXP), block 256 (4 waves). No LDS, no barriers.
// Each wave streams R1 rows of w1 + R1 rows of w3 into registers (coalesced
// float4, 16 loads in flight), then loops matched pairs reading x from L2.
// ---------------------------------------------------------------------------
__global__ __launch_bounds__(256) void moe_gate_up(
    const float* __restrict__ x,     // [TOK][DIM]
    const int*   __restrict__ eidx,  // [TOK][TOPA]
    const float* __restrict__ w1,    // [NEXP][INTER][DIM]
    const float* __restrict__ w3,    // [NEXP][INTER][DIM]
    float*       __restrict__ h)     // [NPAIR][INTER]
{
    const int e    = blockIdx.y;
    const int tid  = threadIdx.x;
    const int lane = tid & 63;
    const int wave = tid >> 6;

    unsigned mask = pair_mask(eidx, e);
    if (!mask) return;   // skip this expert's weights entirely

    const int o0 = blockIdx.x * (4 * R1) + wave * R1;
    const float* w1b = w1 + ((size_t)e * INTER + o0) * DIM;
    const float* w3b = w3 + ((size_t)e * INTER + o0) * DIM;

    // Stream R1 rows of each weight matrix: coalesced float4, all in flight.
    float4 wa[R1][4], wb[R1][4];
    #pragma unroll
    for (int r = 0; r < R1; ++r) {
        #pragma unroll
        for (int k = 0; k < 4; ++k) {
            wa[r][k] = ((const float4*)(w1b + (size_t)r * DIM))[k * 64 + lane];
            wb[r][k] = ((const float4*)(w3b + (size_t)r * DIM))[k * 64 + lane];
        }
    }

    while (mask) {
        const int p = __builtin_ctz(mask);
        mask &= mask - 1;
        const int t = p >> 1;            // p = t*TOPA + a, TOPA = 2

        const float* xr = x + (size_t)t * DIM;
        float4 xv[4];
        #pragma unroll
        for (int k = 0; k < 4; ++k)
            xv[k] = ((const float4*)xr)[k * 64 + lane];

        float s1[R1], s3[R1];
        #pragma unroll
        for (int r = 0; r < R1; ++r) { s1[r] = 0.f; s3[r] = 0.f; }
        #pragma unroll
        for (int k = 0; k < 4; ++k) {
            #pragma unroll
            for (int r = 0; r < R1; ++r) {
                s1[r] += wa[r][k].x * xv[k].x + wa[r][k].y * xv[k].y
                       + wa[r][k].z * xv[k].z + wa[r][k].w * xv[k].w;
                s3[r] += wb[r][k].x * xv[k].x + wb[r][k].y * xv[k].y
                       + wb[r][k].z * xv[k].z + wb[r][k].w * xv[k].w;
            }
        }

        // 64-lane butterfly reduce: 2*R1 independent chains -> ILP.
        #pragma unroll
        for (int off = 32; off > 0; off >>= 1) {
            #pragma unroll
            for (int r = 0; r < R1; ++r) {
                s1[r] += __shfl_xor(s1[r], off);
                s3[r] += __shfl_xor(s3[r], off);
            }
        }

        if (lane == 0) {
            #pragma unroll
            for (int r = 0; r < R1; ++r) {
                const float g = s1[r] / (1.f + __expf(-s1[r]));   // silu
                h[(size_t)p * INTER + o0 + r] = g * s3[r];
            }
        }
    }
}

// ---------------------------------------------------------------------------
// Kernel 2: out[p][d] = sum_o h[p][o] * w2[e][d][o]
// grid: (DIM/(4*R2), NEXP), block 256 (4 waves). No LDS.
// h (360 KB) is L2-resident; read 11 float4/lane per pair.
// ---------------------------------------------------------------------------
__global__ __launch_bounds__(256) void moe_down(
    const float* __restrict__ h,     // [NPAIR][INTER]
    const int*   __restrict__ eidx,  // [TOK][TOPA]
    const float* __restrict__ w2,    // [NEXP][DIM][INTER]
    float*       __restrict__ out)   // [NPAIR][DIM]
{
    const int e    = blockIdx.y;
    const int tid  = threadIdx.x;
    const int lane = tid & 63;
    const int wave = tid >> 6;

    unsigned mask = pair_mask(eidx, e);
    if (!mask) return;

    const int d0 = blockIdx.x * (4 * R2) + wave * R2;
    const float* w2b = w2 + ((size_t)e * DIM + d0) * INTER;

    // Stream R2 rows of w2: 2816 f32 = 11 float4/lane each, all in flight.
    float4 wv[R2][11];
    #pragma unroll
    for (int r = 0; r < R2; ++r) {
        #pragma unroll
        for (int k = 0; k < 11; ++k)
            wv[r][k] = ((const float4*)(w2b + (size_t)r * INTER))[k * 64 + lane];
    }

    while (mask) {
        const int p = __builtin_ctz(mask);
        mask &= mask - 1;

        const float* hr = h + (size_t)p * INTER;
        float s[R2];
        #pragma unroll
        for (int r = 0; r < R2; ++r) s[r] = 0.f;

        #pragma unroll
        for (int k = 0; k < 11; ++k) {
            const float4 hv = ((const float4*)hr)[k * 64 + lane];
            #pragma unroll
            for (int r = 0; r < R2; ++r) {
                s[r] += wv[r][k].x * hv.x + wv[r][k].y * hv.y
                      + wv[r][k].z * hv.z + wv[r][k].w * hv.w;
            }
        }

        #pragma unroll
        for (int off = 32; off > 0; off >>= 1) {
            #pragma unroll
            for (int r = 0; r < R2; ++r)
                s[r] += __shfl_xor(s[r], off);
        }

        if (lane == 0) {
            #pragma unroll
            for (int r = 0; r < R2; ++r)
                out[(size_t)p * DIM + d0 + r] = s[r];
        }
    }
}

// ---------------------------------------------------------------------------
extern "C" void kernel_launch(void* const* d_in, const int* in_sizes, int n_in,
                              void* d_out, int out_size, void* d_ws, size_t ws_size,
                              hipStream_t stream) {
    const float* x    = (const float*)d_in[0];
    const int*   eidx = (const int*)  d_in[1];
    const float* w1   = (const float*)d_in[2];
    const float* w2   = (const float*)d_in[3];
    const float* w3   = (const float*)d_in[4];
    float* out = (float*)d_out;
    float* h   = (float*)d_ws;   // [NPAIR][INTER] f32 = 360448 B

    dim3 g1(INTER / (4 * R1), NEXP);
    moe_gate_up<<<g1, 256, 0, stream>>>(x, eidx, w1, w3, h);

    dim3 g2(DIM / (4 * R2), NEXP);
    moe_down<<<g2, 256, 0, stream>>>(h, eidx, w2, out);
}